// Round 12
// baseline (178.278 us; speedup 1.0000x reference)
//
#include <hip/hip_runtime.h>
#include <hip/hip_bf16.h>
#include <math.h>

// SS2D (VMamba) forward, MI355X. Constants from the reference.
#define DM 96
#define DI 192
#define NS 16            // state dim N
#define KK 4             // directions
#define RR 6             // dt rank
#define HH 56
#define WW 56
#define LL (HH*WW)       // 3136
#define RN (RR + 2*NS)   // 38 rows of x_dbl
#define NCH 64           // scan chunks per sequence
#define CLL (LL/NCH)     // 49 steps per chunk

__device__ __forceinline__ float silu_f(float x) { return x / (1.f + __expf(-x)); }
__device__ __forceinline__ float softplus_f(float x) {
    return (x > 20.f) ? x : log1pf(__expf(x));
}

// K1: tiled GEMM xz[o][l]; 32l x 32o tiles, grid (98, 12).
// o<DI -> xc_t[o][l]; o>=DI -> silu -> z_nat[l][o-DI]
__global__ __launch_bounds__(256) void k_inproj(
        const float* __restrict__ x, const float* __restrict__ w,
        float* __restrict__ xc_t, float* __restrict__ z_nat) {
    __shared__ float xt[32 * 100];
    __shared__ float wt[32 * 100];
    const int l0 = blockIdx.x * 32;
    const int o0 = blockIdx.y * 32;
    const int tid = threadIdx.x;
    for (int i = tid; i < 32 * 24; i += 256) {          // float4 staging
        int r = i / 24, q = i % 24;
        *(float4*)&xt[r * 100 + 4 * q] = *(const float4*)&x[(size_t)(l0 + r) * DM + 4 * q];
        *(float4*)&wt[r * 100 + 4 * q] = *(const float4*)&w[(size_t)(o0 + r) * DM + 4 * q];
    }
    __syncthreads();
    const int tx = tid & 15, ty = tid >> 4;        // tx: o, ty: l
    float acc[2][2] = {};
    for (int c = 0; c < 96; c += 4) {
        float4 av[2], bv[2];
#pragma unroll
        for (int i = 0; i < 2; ++i) av[i] = *(const float4*)&xt[(ty + 16 * i) * 100 + c];
#pragma unroll
        for (int j = 0; j < 2; ++j) bv[j] = *(const float4*)&wt[(tx + 16 * j) * 100 + c];
#pragma unroll
        for (int i = 0; i < 2; ++i)
#pragma unroll
            for (int j = 0; j < 2; ++j) {
                acc[i][j] = fmaf(av[i].x, bv[j].x, acc[i][j]);
                acc[i][j] = fmaf(av[i].y, bv[j].y, acc[i][j]);
                acc[i][j] = fmaf(av[i].z, bv[j].z, acc[i][j]);
                acc[i][j] = fmaf(av[i].w, bv[j].w, acc[i][j]);
            }
    }
    __syncthreads();
    float* ot = xt;                                // reuse as [o][l] 32x65
#pragma unroll
    for (int j = 0; j < 2; ++j)
#pragma unroll
        for (int i = 0; i < 2; ++i)
            ot[(tx + 16 * j) * 65 + (ty + 16 * i)] = acc[i][j];
    __syncthreads();
    if (o0 < DI) {
        for (int i = tid; i < 32 * 32; i += 256) {
            int ol = i >> 5, ll = i & 31;
            xc_t[(size_t)(o0 + ol) * LL + l0 + ll] = ot[ol * 65 + ll];
        }
    } else {
        for (int i = tid; i < 32 * 32; i += 256) {
            int ll = i >> 5, ol = i & 31;
            z_nat[(size_t)(l0 + ll) * DI + (o0 - DI) + ol] = silu_f(ot[ol * 65 + ll]);
        }
    }
}

// K2: depthwise 3x3 conv SAME + bias + silu + spatial transpose, band-split.
__global__ __launch_bounds__(256) void k_convT(
        const float* __restrict__ xc_t, const float* __restrict__ cw,
        const float* __restrict__ cb, float* __restrict__ xconv, float* __restrict__ xs1) {
    __shared__ float in_s[16 * 56];
    __shared__ float out_s[14 * 57];
    const int d = blockIdx.x;
    const int h0 = blockIdx.y * 14;
    const int tid = threadIdx.x;
    const float* in = xc_t + (size_t)d * LL;
    for (int i = tid; i < 16 * 14; i += 256) {          // float4 staging
        int row = i / 14, q = i % 14;
        int r = row - 1 + h0;
        float4 v = make_float4(0.f, 0.f, 0.f, 0.f);
        if (r >= 0 && r < HH) v = *(const float4*)&in[r * WW + 4 * q];
        *(float4*)&in_s[row * 56 + 4 * q] = v;
    }
    __syncthreads();
    const float b0 = cb[d];
    float w9[9];
#pragma unroll
    for (int i = 0; i < 9; ++i) w9[i] = cw[d * 9 + i];
    for (int i = tid; i < 14 * 56; i += 256) {
        int hh = i / 56, w = i % 56;
        float acc = b0;
#pragma unroll
        for (int di = 0; di < 3; ++di)
#pragma unroll
            for (int dj = 0; dj < 3; ++dj) {
                int w2 = w + dj - 1;
                if (w2 < 0 || w2 >= WW) continue;
                acc = fmaf(in_s[(hh + di) * 56 + w2], w9[di * 3 + dj], acc);
            }
        acc = silu_f(acc);
        xconv[(size_t)d * LL + (h0 + hh) * WW + w] = acc;
        out_s[hh * 57 + w] = acc;
    }
    __syncthreads();
    for (int i = tid; i < 14 * 56; i += 256) {
        int w = i / 14, hh = i % 14;
        xs1[(size_t)d * LL + w * HH + h0 + hh] = out_s[hh * 57 + w];
    }
}

// K3: x_dbl + delta fused, l-tile 16. Both operands LDS-staged. Grid (196, 4).
__global__ __launch_bounds__(256) void k_xdblD(
        const float* __restrict__ xconv, const float* __restrict__ xs1,
        const float* __restrict__ pw, const float* __restrict__ dtw,
        const float* __restrict__ dtb,
        float* __restrict__ Bn, float* __restrict__ Cn, float* __restrict__ delta) {
    __shared__ float xt[DI * 16];                  // [d][sx], 12 KB
    __shared__ float wk_s[32 * DI];                // [col][d], 24.6 KB
    __shared__ float dtS[RR * 17];
    const int k = blockIdx.y;
    const int l0 = blockIdx.x * 16;
    const int tid = threadIdx.x;
    const float* in = (k & 1) ? xs1 : xconv;
    const float* wk = pw + (size_t)k * RN * DI;
    for (int i = tid; i < DI * 4; i += 256) {          // float4 staging
        int d = i >> 2, q = i & 3;
        *(float4*)&xt[(d << 4) + 4 * q] = *(const float4*)&in[(size_t)d * LL + l0 + 4 * q];
    }
    {
        const float4* src = (const float4*)(wk + RR * DI);
        float4* dst = (float4*)wk_s;
        for (int i = tid; i < (32 * DI) / 4; i += 256) dst[i] = src[i];
    }
    __syncthreads();
    if (tid < RR * 16) {
        int r = tid >> 4, lx = tid & 15;
        const float* wr = wk + r * DI;
        float acc = 0.f;
#pragma unroll 8
        for (int d = 0; d < DI; ++d) acc = fmaf(xt[(d << 4) + lx], wr[d], acc);
        dtS[r * 17 + lx] = acc;
    }
    {
        const int sx = tid & 15, cg = tid >> 4;    // cg in [0,16)
        float acc2[2] = {};
        for (int d = 0; d < DI; d += 4) {
            float x0 = xt[(d + 0) * 16 + sx];
            float x1 = xt[(d + 1) * 16 + sx];
            float x2 = xt[(d + 2) * 16 + sx];
            float x3 = xt[(d + 3) * 16 + sx];
#pragma unroll
            for (int j = 0; j < 2; ++j) {
                float4 wv = *(const float4*)&wk_s[(cg + 16 * j) * DI + d];
                acc2[j] = fmaf(x0, wv.x, acc2[j]);
                acc2[j] = fmaf(x1, wv.y, acc2[j]);
                acc2[j] = fmaf(x2, wv.z, acc2[j]);
                acc2[j] = fmaf(x3, wv.w, acc2[j]);
            }
        }
        int s = l0 + sx;
        Bn[((size_t)k * LL + s) * NS + cg] = acc2[0];   // cols 0..15
        Cn[((size_t)k * LL + s) * NS + cg] = acc2[1];   // cols 16..31
    }
    __syncthreads();
    for (int oi = tid; oi < DI * 16; oi += 256) {
        int d = oi >> 4, sl = oi & 15;
        int kd = k * DI + d;
        const float* wr = dtw + (size_t)kd * RR;
        float acc = dtb[kd];
#pragma unroll
        for (int r = 0; r < RR; ++r) acc = fmaf(dtS[r * 17 + sl], wr[r], acc);
        delta[(size_t)kd * LL + l0 + sl] = softplus_f(acc);
    }
}

// ---- templated scan body (R9-proven): STP = +/-1 literal strides; TRANS routes
// the output through a padded LDS tile so k-odd directions land in NATURAL space.
template<int STP, bool TRANS>
__device__ __forceinline__ void scan_dir(
        const float* __restrict__ pd, const float* __restrict__ pu,
        const float* __restrict__ pB, const float* __restrict__ pC,
        float An, float Dv, int c, int n,
        float* __restrict__ sP, float* __restrict__ sH,
        float* __restrict__ yo0,   // !TRANS: direction-adjusted global base
        float* __restrict__ ysm,   // TRANS: LDS tile [HH][57]
        int im0) {
    // Phase 1: chunk-local scan (h=0 start); P = exp(An * sum(dl))
    float sd = 0.f, h = 0.f;
#pragma unroll 7
    for (int tl = 0; tl < CLL; ++tl) {
        float dl = pd[STP * tl];
        float u  = pu[STP * tl];
        float Bv = pB[STP * NS * tl];
        float dA = __expf(dl * An);
        h = fmaf(dA, h, dl * Bv * u);
        sd += dl;
    }
    sP[c * NS + n] = __expf(sd * An);
    sH[c * NS + n] = h;
    __syncthreads();
    float hin = 0.f;
    for (int cc = 0; cc < c; ++cc)
        hin = fmaf(sP[cc * NS + n], hin, sH[cc * NS + n]);

    // Phase 2: rescan with carry, emit y
    float h2 = hin;
    float yreg[4];
#pragma unroll 7
    for (int tl = 0; tl < CLL; ++tl) {
        float dl = pd[STP * tl];
        float u  = pu[STP * tl];
        float Bv = pB[STP * NS * tl];
        float Cv = pC[STP * NS * tl];
        float dA = __expf(dl * An);
        h2 = fmaf(dA, h2, dl * Bv * u);
        float acc = h2 * Cv;
        acc += __shfl_xor(acc, 8, 64);
        acc += __shfl_xor(acc, 4, 64);
        acc += __shfl_xor(acc, 2, 64);
        acc += __shfl_xor(acc, 1, 64);
        acc = fmaf(Dv, u, acc);
        if ((tl & 15) == n) yreg[tl >> 4] = acc;
    }
    if (!TRANS) {
#pragma unroll
        for (int j = 0; j < 3; ++j)
            yo0[STP * (j * 16 + n)] = yreg[j];
        if (n == 0)
            yo0[STP * 48] = yreg[3];
    } else {
#pragma unroll
        for (int j = 0; j < 3; ++j) {
            int im = im0 + STP * (j * 16 + n);
            int w = im / HH, hh = im - w * HH;
            ysm[hh * 57 + w] = yreg[j];
        }
        if (n == 0) {
            int im = im0 + STP * 48;
            int w = im / HH, hh = im - w * HH;
            ysm[hh * 57 + w] = yreg[3];
        }
    }
}

// K4: chunked selective scan; all 4 directions written to y4[kd][p] in NATURAL space.
__global__ __launch_bounds__(1024) void k_scan(
        const float* __restrict__ delta, const float* __restrict__ Bn,
        const float* __restrict__ Cn,
        const float* __restrict__ xconv, const float* __restrict__ xs1,
        const float* __restrict__ A_logs, const float* __restrict__ Ds,
        float* __restrict__ y4) {
    __shared__ float sP[NCH * NS];
    __shared__ float sH[NCH * NS];
    __shared__ float ys[HH * 57];                  // k-odd transpose tile
    int b = blockIdx.x;
    int k = b / DI, d = b % DI;
    int tid = threadIdx.x;
    int c = tid >> 4, n = tid & 15;
    int kd = k * DI + d;
    float An = -__expf(A_logs[kd * NS + n]);
    float Dv = Ds[kd];
    const float* del = delta + (size_t)kd * LL;
    const float* uP  = ((k & 1) ? xs1 : xconv) + (size_t)d * LL;
    const float* Bb  = Bn + (size_t)k * LL * NS;
    const float* Cb  = Cn + (size_t)k * LL * NS;
    float* yo = y4 + (size_t)kd * LL;
    const int t0 = c * CLL;
    const int imF = t0;                  // forward base
    const int imR = LL - 1 - t0;         // reverse base
    if (k == 0) {
        scan_dir<1, false>(del + imF, uP + imF,
                           Bb + (size_t)imF * NS + n, Cb + (size_t)imF * NS + n,
                           An, Dv, c, n, sP, sH, yo + imF, nullptr, 0);
    } else if (k == 1) {
        scan_dir<1, true>(del + imF, uP + imF,
                          Bb + (size_t)imF * NS + n, Cb + (size_t)imF * NS + n,
                          An, Dv, c, n, sP, sH, nullptr, ys, imF);
    } else if (k == 2) {
        scan_dir<-1, false>(del + imR, uP + imR,
                            Bb + (size_t)imR * NS + n, Cb + (size_t)imR * NS + n,
                            An, Dv, c, n, sP, sH, yo + imR, nullptr, 0);
    } else {
        scan_dir<-1, true>(del + imR, uP + imR,
                           Bb + (size_t)imR * NS + n, Cb + (size_t)imR * NS + n,
                           An, Dv, c, n, sP, sH, nullptr, ys, imR);
    }
    if (k & 1) {                         // block-uniform branch
        __syncthreads();
        for (int p = tid; p < LL; p += 1024)
            yo[p] = ys[p + p / WW];      // [h][w] tile, stride 57
    }
}

// K5: merge 4 natural rows + LayerNorm + gate(z) ONCE, then out-proj in two
// sequential 48-o passes (ow_s restaged). 16 l per block; grid 196.
__global__ __launch_bounds__(256) void k_lnout(
        const float* __restrict__ y4, const float* __restrict__ z_nat,
        const float* __restrict__ lnw, const float* __restrict__ lnb,
        const float* __restrict__ ow, float* __restrict__ out) {
    __shared__ float yv[16 * 196];                 // 12.5 KB
    __shared__ float ow_s[48 * 196];               // 37.6 KB
    __shared__ float mean_s[16], inv_s[16];
    const int l0 = blockIdx.x * 16;
    const int tid = threadIdx.x;
    // merge 4 directions: float4 over p for each d
    for (int i = tid; i < DI * 4; i += 256) {
        int d = i >> 2, q = i & 3;
        size_t off = (size_t)d * LL + l0 + 4 * q;
        float4 a = *(const float4*)&y4[off];
        float4 b = *(const float4*)&y4[(size_t)DI * LL + off];
        float4 c2 = *(const float4*)&y4[(size_t)(2 * DI) * LL + off];
        float4 e = *(const float4*)&y4[(size_t)(3 * DI) * LL + off];
        int p = 4 * q;
        yv[(p + 0) * 196 + d] = a.x + b.x + c2.x + e.x;
        yv[(p + 1) * 196 + d] = a.y + b.y + c2.y + e.y;
        yv[(p + 2) * 196 + d] = a.z + b.z + c2.z + e.z;
        yv[(p + 3) * 196 + d] = a.w + b.w + c2.w + e.w;
    }
    __syncthreads();
    // LN stats: 16 lanes per p
    {
        int p = tid >> 4, e = tid & 15;
        float s1 = 0.f;
#pragma unroll
        for (int m = 0; m < 12; ++m) s1 += yv[p * 196 + e + 16 * m];
        s1 += __shfl_xor(s1, 8, 64);
        s1 += __shfl_xor(s1, 4, 64);
        s1 += __shfl_xor(s1, 2, 64);
        s1 += __shfl_xor(s1, 1, 64);
        float mean = s1 * (1.f / DI);
        float s2 = 0.f;
#pragma unroll
        for (int m = 0; m < 12; ++m) {
            float dv = yv[p * 196 + e + 16 * m] - mean;
            s2 = fmaf(dv, dv, s2);
        }
        s2 += __shfl_xor(s2, 8, 64);
        s2 += __shfl_xor(s2, 4, 64);
        s2 += __shfl_xor(s2, 2, 64);
        s2 += __shfl_xor(s2, 1, 64);
        if (e == 0) {
            mean_s[p] = mean;
            inv_s[p] = rsqrtf(s2 * (1.f / DI) + 1e-5f);
        }
    }
    __syncthreads();
    // normalize + gate (float4 over d) — done ONCE
    for (int i = tid; i < 16 * 48; i += 256) {
        int p = i / 48, q = i % 48;
        float4 z4 = *(const float4*)&z_nat[(size_t)(l0 + p) * DI + 4 * q];
        float4 w4 = *(const float4*)&lnw[4 * q];
        float4 b4 = *(const float4*)&lnb[4 * q];
        float4 yy = *(const float4*)&yv[p * 196 + 4 * q];
        float m = mean_s[p], iv = inv_s[p];
        yy.x = ((yy.x - m) * iv * w4.x + b4.x) * z4.x;
        yy.y = ((yy.y - m) * iv * w4.y + b4.y) * z4.y;
        yy.z = ((yy.z - m) * iv * w4.z + b4.z) * z4.z;
        yy.w = ((yy.w - m) * iv * w4.w + b4.w) * z4.w;
        *(float4*)&yv[p * 196 + 4 * q] = yy;
    }
    // out-proj: two sequential 48-o passes, restaging ow_s
    const int ty = tid >> 4, tx = tid & 15;        // ty: l, tx: o
#pragma unroll
    for (int pass = 0; pass < 2; ++pass) {
        __syncthreads();                            // writers of pass-1 ow_s wait for readers
        for (int i = tid; i < 48 * 48; i += 256) {
            int o = i / 48, q = i % 48;
            *(float4*)&ow_s[o * 196 + 4 * q] =
                *(const float4*)&ow[(size_t)(pass * 48 + o) * DI + 4 * q];
        }
        __syncthreads();
        float acc[3] = {};
        for (int dd = 0; dd < DI; dd += 4) {
            float4 a0 = *(const float4*)&yv[ty * 196 + dd];
#pragma unroll
            for (int j = 0; j < 3; ++j) {
                float4 bv = *(const float4*)&ow_s[(tx + 16 * j) * 196 + dd];
                acc[j] += a0.x * bv.x + a0.y * bv.y + a0.z * bv.z + a0.w * bv.w;
            }
        }
#pragma unroll
        for (int j = 0; j < 3; ++j)
            out[(size_t)(l0 + ty) * DM + pass * 48 + tx + 16 * j] = acc[j];
    }
}

extern "C" void kernel_launch(void* const* d_in, const int* in_sizes, int n_in,
                              void* d_out, int out_size, void* d_ws, size_t ws_size,
                              hipStream_t stream) {
    const float* x    = (const float*)d_in[0];
    const float* ipw  = (const float*)d_in[1];
    const float* cw   = (const float*)d_in[2];
    const float* cb   = (const float*)d_in[3];
    const float* xpw  = (const float*)d_in[4];
    const float* dtw  = (const float*)d_in[5];
    const float* dtb  = (const float*)d_in[6];
    const float* alog = (const float*)d_in[7];
    const float* Dsp  = (const float*)d_in[8];
    const float* lnw  = (const float*)d_in[9];
    const float* lnb  = (const float*)d_in[10];
    const float* ow   = (const float*)d_in[11];
    float* out = (float*)d_out;

    float* ws     = (float*)d_ws;
    float* xc_t   = ws;                             // DI*LL (dead after convT)
    float* z_nat  = xc_t + DI * LL;                 // LL*DI
    float* xconv  = z_nat + DI * LL;                // DI*LL
    float* xs1    = xconv + DI * LL;                // DI*LL
    float* Bn     = xs1 + DI * LL;                  // KK*LL*NS
    float* Cn     = Bn + (size_t)KK * LL * NS;      // KK*LL*NS
    float* delta  = Cn + (size_t)KK * LL * NS;      // KK*DI*LL
    float* y4     = delta + (size_t)KK * DI * LL;   // KK*DI*LL (natural p)

    k_inproj <<<dim3(LL / 32, 12), 256, 0, stream>>>(x, ipw, xc_t, z_nat);
    k_convT  <<<dim3(DI, 4), 256, 0, stream>>>(xc_t, cw, cb, xconv, xs1);
    k_xdblD  <<<dim3(LL / 16, KK), 256, 0, stream>>>(xconv, xs1, xpw, dtw, dtb, Bn, Cn, delta);
    k_scan   <<<KK * DI, 1024, 0, stream>>>(delta, Bn, Cn, xconv, xs1, alog, Dsp, y4);
    k_lnout  <<<LL / 16, 256, 0, stream>>>(y4, z_nat, lnw, lnb, ow, out);
}

// Round 13
// 176.461 us; speedup vs baseline: 1.0103x; 1.0103x over previous
//
#include <hip/hip_runtime.h>
#include <hip/hip_bf16.h>
#include <math.h>

// SS2D (VMamba) forward, MI355X. Constants from the reference.
#define DM 96
#define DI 192
#define NS 16            // state dim N
#define KK 4             // directions
#define RR 6             // dt rank
#define HH 56
#define WW 56
#define LL (HH*WW)       // 3136
#define RN (RR + 2*NS)   // 38 rows of x_dbl
#define NCH 64           // scan chunks per sequence
#define CLL (LL/NCH)     // 49 steps per chunk

__device__ __forceinline__ float silu_f(float x) { return x / (1.f + __expf(-x)); }
__device__ __forceinline__ float softplus_f(float x) {
    return (x > 20.f) ? x : log1pf(__expf(x));
}

// K1: tiled GEMM xz[o][l]; 32l x 32o tiles, grid (98, 12).
// o<DI -> xc_t[o][l]; o>=DI -> silu -> z_nat[l][o-DI]
__global__ __launch_bounds__(256) void k_inproj(
        const float* __restrict__ x, const float* __restrict__ w,
        float* __restrict__ xc_t, float* __restrict__ z_nat) {
    __shared__ float xt[32 * 100];
    __shared__ float wt[32 * 100];
    const int l0 = blockIdx.x * 32;
    const int o0 = blockIdx.y * 32;
    const int tid = threadIdx.x;
    for (int i = tid; i < 32 * 24; i += 256) {          // float4 staging
        int r = i / 24, q = i % 24;
        *(float4*)&xt[r * 100 + 4 * q] = *(const float4*)&x[(size_t)(l0 + r) * DM + 4 * q];
        *(float4*)&wt[r * 100 + 4 * q] = *(const float4*)&w[(size_t)(o0 + r) * DM + 4 * q];
    }
    __syncthreads();
    const int tx = tid & 15, ty = tid >> 4;        // tx: o, ty: l
    float acc[2][2] = {};
    for (int c = 0; c < 96; c += 4) {
        float4 av[2], bv[2];
#pragma unroll
        for (int i = 0; i < 2; ++i) av[i] = *(const float4*)&xt[(ty + 16 * i) * 100 + c];
#pragma unroll
        for (int j = 0; j < 2; ++j) bv[j] = *(const float4*)&wt[(tx + 16 * j) * 100 + c];
#pragma unroll
        for (int i = 0; i < 2; ++i)
#pragma unroll
            for (int j = 0; j < 2; ++j) {
                acc[i][j] = fmaf(av[i].x, bv[j].x, acc[i][j]);
                acc[i][j] = fmaf(av[i].y, bv[j].y, acc[i][j]);
                acc[i][j] = fmaf(av[i].z, bv[j].z, acc[i][j]);
                acc[i][j] = fmaf(av[i].w, bv[j].w, acc[i][j]);
            }
    }
    __syncthreads();
    float* ot = xt;                                // reuse as [o][l] 32x65
#pragma unroll
    for (int j = 0; j < 2; ++j)
#pragma unroll
        for (int i = 0; i < 2; ++i)
            ot[(tx + 16 * j) * 65 + (ty + 16 * i)] = acc[i][j];
    __syncthreads();
    if (o0 < DI) {
        for (int i = tid; i < 32 * 32; i += 256) {
            int ol = i >> 5, ll = i & 31;
            xc_t[(size_t)(o0 + ol) * LL + l0 + ll] = ot[ol * 65 + ll];
        }
    } else {
        for (int i = tid; i < 32 * 32; i += 256) {
            int ll = i >> 5, ol = i & 31;
            z_nat[(size_t)(l0 + ll) * DI + (o0 - DI) + ol] = silu_f(ot[ol * 65 + ll]);
        }
    }
}

// K2: depthwise 3x3 conv SAME + bias + silu + spatial transpose, band-split.
__global__ __launch_bounds__(256) void k_convT(
        const float* __restrict__ xc_t, const float* __restrict__ cw,
        const float* __restrict__ cb, float* __restrict__ xconv, float* __restrict__ xs1) {
    __shared__ float in_s[16 * 56];
    __shared__ float out_s[14 * 57];
    const int d = blockIdx.x;
    const int h0 = blockIdx.y * 14;
    const int tid = threadIdx.x;
    const float* in = xc_t + (size_t)d * LL;
    for (int i = tid; i < 16 * 14; i += 256) {          // float4 staging
        int row = i / 14, q = i % 14;
        int r = row - 1 + h0;
        float4 v = make_float4(0.f, 0.f, 0.f, 0.f);
        if (r >= 0 && r < HH) v = *(const float4*)&in[r * WW + 4 * q];
        *(float4*)&in_s[row * 56 + 4 * q] = v;
    }
    __syncthreads();
    const float b0 = cb[d];
    float w9[9];
#pragma unroll
    for (int i = 0; i < 9; ++i) w9[i] = cw[d * 9 + i];
    for (int i = tid; i < 14 * 56; i += 256) {
        int hh = i / 56, w = i % 56;
        float acc = b0;
#pragma unroll
        for (int di = 0; di < 3; ++di)
#pragma unroll
            for (int dj = 0; dj < 3; ++dj) {
                int w2 = w + dj - 1;
                if (w2 < 0 || w2 >= WW) continue;
                acc = fmaf(in_s[(hh + di) * 56 + w2], w9[di * 3 + dj], acc);
            }
        acc = silu_f(acc);
        xconv[(size_t)d * LL + (h0 + hh) * WW + w] = acc;
        out_s[hh * 57 + w] = acc;
    }
    __syncthreads();
    for (int i = tid; i < 14 * 56; i += 256) {
        int w = i / 14, hh = i % 14;
        xs1[(size_t)d * LL + w * HH + h0 + hh] = out_s[hh * 57 + w];
    }
}

// K3: x_dbl + delta fused, l-tile 16. Both operands LDS-staged. Grid (196, 4).
__global__ __launch_bounds__(256) void k_xdblD(
        const float* __restrict__ xconv, const float* __restrict__ xs1,
        const float* __restrict__ pw, const float* __restrict__ dtw,
        const float* __restrict__ dtb,
        float* __restrict__ Bn, float* __restrict__ Cn, float* __restrict__ delta) {
    __shared__ float xt[DI * 16];                  // [d][sx], 12 KB
    __shared__ float wk_s[32 * DI];                // [col][d], 24.6 KB
    __shared__ float dtS[RR * 17];
    const int k = blockIdx.y;
    const int l0 = blockIdx.x * 16;
    const int tid = threadIdx.x;
    const float* in = (k & 1) ? xs1 : xconv;
    const float* wk = pw + (size_t)k * RN * DI;
    for (int i = tid; i < DI * 4; i += 256) {          // float4 staging
        int d = i >> 2, q = i & 3;
        *(float4*)&xt[(d << 4) + 4 * q] = *(const float4*)&in[(size_t)d * LL + l0 + 4 * q];
    }
    {
        const float4* src = (const float4*)(wk + RR * DI);
        float4* dst = (float4*)wk_s;
        for (int i = tid; i < (32 * DI) / 4; i += 256) dst[i] = src[i];
    }
    __syncthreads();
    if (tid < RR * 16) {
        int r = tid >> 4, lx = tid & 15;
        const float* wr = wk + r * DI;
        float acc = 0.f;
#pragma unroll 8
        for (int d = 0; d < DI; ++d) acc = fmaf(xt[(d << 4) + lx], wr[d], acc);
        dtS[r * 17 + lx] = acc;
    }
    {
        const int sx = tid & 15, cg = tid >> 4;    // cg in [0,16)
        float acc2[2] = {};
        for (int d = 0; d < DI; d += 4) {
            float x0 = xt[(d + 0) * 16 + sx];
            float x1 = xt[(d + 1) * 16 + sx];
            float x2 = xt[(d + 2) * 16 + sx];
            float x3 = xt[(d + 3) * 16 + sx];
#pragma unroll
            for (int j = 0; j < 2; ++j) {
                float4 wv = *(const float4*)&wk_s[(cg + 16 * j) * DI + d];
                acc2[j] = fmaf(x0, wv.x, acc2[j]);
                acc2[j] = fmaf(x1, wv.y, acc2[j]);
                acc2[j] = fmaf(x2, wv.z, acc2[j]);
                acc2[j] = fmaf(x3, wv.w, acc2[j]);
            }
        }
        int s = l0 + sx;
        Bn[((size_t)k * LL + s) * NS + cg] = acc2[0];   // cols 0..15
        Cn[((size_t)k * LL + s) * NS + cg] = acc2[1];   // cols 16..31
    }
    __syncthreads();
    for (int oi = tid; oi < DI * 16; oi += 256) {
        int d = oi >> 4, sl = oi & 15;
        int kd = k * DI + d;
        const float* wr = dtw + (size_t)kd * RR;
        float acc = dtb[kd];
#pragma unroll
        for (int r = 0; r < RR; ++r) acc = fmaf(dtS[r * 17 + sl], wr[r], acc);
        delta[(size_t)kd * LL + l0 + sl] = softplus_f(acc);
    }
}

// ---- templated scan body: 8 lanes per chunk, 2 states per lane (n and n+8).
// STP = +/-1 literal strides; TRANS routes output through a padded LDS tile.
template<int STP, bool TRANS>
__device__ __forceinline__ void scan_dir(
        const float* __restrict__ pd, const float* __restrict__ pu,
        const float* __restrict__ pB, const float* __restrict__ pC, // at +n; second state at +8
        float An0, float An1, float Dv, int c, int n,
        float* __restrict__ sP, float* __restrict__ sH,
        float* __restrict__ yo0,   // !TRANS: direction-adjusted global base
        float* __restrict__ ysm,   // TRANS: LDS tile [HH][57]
        int im0) {
    // Phase 1: chunk-local scan (h=0 start); P = exp(An * sum(dl))
    float sd = 0.f, h0 = 0.f, h1 = 0.f;
#pragma unroll 7
    for (int tl = 0; tl < CLL; ++tl) {
        float dl = pd[STP * tl];
        float u  = pu[STP * tl];
        float B0 = pB[STP * NS * tl];
        float B1 = pB[STP * NS * tl + 8];
        float dA0 = __expf(dl * An0);
        float dA1 = __expf(dl * An1);
        float du = dl * u;
        h0 = fmaf(dA0, h0, du * B0);
        h1 = fmaf(dA1, h1, du * B1);
        sd += dl;
    }
    sP[c * NS + n]     = __expf(sd * An0);
    sP[c * NS + n + 8] = __expf(sd * An1);
    sH[c * NS + n]     = h0;
    sH[c * NS + n + 8] = h1;
    __syncthreads();
    float hin0 = 0.f, hin1 = 0.f;
    for (int cc = 0; cc < c; ++cc) {
        hin0 = fmaf(sP[cc * NS + n],     hin0, sH[cc * NS + n]);
        hin1 = fmaf(sP[cc * NS + n + 8], hin1, sH[cc * NS + n + 8]);
    }

    // Phase 2: rescan with carry, emit y
    float h20 = hin0, h21 = hin1;
    float yreg[7];
#pragma unroll 7
    for (int tl = 0; tl < CLL; ++tl) {
        float dl = pd[STP * tl];
        float u  = pu[STP * tl];
        float B0 = pB[STP * NS * tl];
        float B1 = pB[STP * NS * tl + 8];
        float C0 = pC[STP * NS * tl];
        float C1 = pC[STP * NS * tl + 8];
        float dA0 = __expf(dl * An0);
        float dA1 = __expf(dl * An1);
        float du = dl * u;
        h20 = fmaf(dA0, h20, du * B0);
        h21 = fmaf(dA1, h21, du * B1);
        float acc = h20 * C0 + h21 * C1;
        acc += __shfl_xor(acc, 4, 64);
        acc += __shfl_xor(acc, 2, 64);
        acc += __shfl_xor(acc, 1, 64);
        acc = fmaf(Dv, u, acc);
        if ((tl & 7) == n) yreg[tl >> 3] = acc;
    }
    if (!TRANS) {
#pragma unroll
        for (int j = 0; j < 6; ++j)
            yo0[STP * (j * 8 + n)] = yreg[j];
        if (n == 0)
            yo0[STP * 48] = yreg[6];
    } else {
#pragma unroll
        for (int j = 0; j < 6; ++j) {
            int im = im0 + STP * (j * 8 + n);
            int w = im / HH, hh = im - w * HH;
            ysm[hh * 57 + w] = yreg[j];
        }
        if (n == 0) {
            int im = im0 + STP * 48;
            int w = im / HH, hh = im - w * HH;
            ysm[hh * 57 + w] = yreg[6];
        }
    }
}

// K4: chunked selective scan; 512 threads (8 waves -> 3-4 blocks/CU resident).
// All 4 directions written to y4[kd][p] in NATURAL space.
__global__ __launch_bounds__(512) void k_scan(
        const float* __restrict__ delta, const float* __restrict__ Bn,
        const float* __restrict__ Cn,
        const float* __restrict__ xconv, const float* __restrict__ xs1,
        const float* __restrict__ A_logs, const float* __restrict__ Ds,
        float* __restrict__ y4) {
    __shared__ float sP[NCH * NS];
    __shared__ float sH[NCH * NS];
    __shared__ float ys[HH * 57];                  // k-odd transpose tile
    int b = blockIdx.x;
    int k = b / DI, d = b % DI;
    int tid = threadIdx.x;
    int c = tid >> 3, n = tid & 7;
    int kd = k * DI + d;
    float An0 = -__expf(A_logs[kd * NS + n]);
    float An1 = -__expf(A_logs[kd * NS + n + 8]);
    float Dv = Ds[kd];
    const float* del = delta + (size_t)kd * LL;
    const float* uP  = ((k & 1) ? xs1 : xconv) + (size_t)d * LL;
    const float* Bb  = Bn + (size_t)k * LL * NS;
    const float* Cb  = Cn + (size_t)k * LL * NS;
    float* yo = y4 + (size_t)kd * LL;
    const int t0 = c * CLL;
    const int imF = t0;                  // forward base
    const int imR = LL - 1 - t0;         // reverse base
    if (k == 0) {
        scan_dir<1, false>(del + imF, uP + imF,
                           Bb + (size_t)imF * NS + n, Cb + (size_t)imF * NS + n,
                           An0, An1, Dv, c, n, sP, sH, yo + imF, nullptr, 0);
    } else if (k == 1) {
        scan_dir<1, true>(del + imF, uP + imF,
                          Bb + (size_t)imF * NS + n, Cb + (size_t)imF * NS + n,
                          An0, An1, Dv, c, n, sP, sH, nullptr, ys, imF);
    } else if (k == 2) {
        scan_dir<-1, false>(del + imR, uP + imR,
                            Bb + (size_t)imR * NS + n, Cb + (size_t)imR * NS + n,
                            An0, An1, Dv, c, n, sP, sH, yo + imR, nullptr, 0);
    } else {
        scan_dir<-1, true>(del + imR, uP + imR,
                           Bb + (size_t)imR * NS + n, Cb + (size_t)imR * NS + n,
                           An0, An1, Dv, c, n, sP, sH, nullptr, ys, imR);
    }
    if (k & 1) {                         // block-uniform branch
        __syncthreads();
        for (int p = tid; p < LL; p += 512)
            yo[p] = ys[p + p / WW];      // [h][w] tile, stride 57
    }
}

// K5: merge 4 natural rows + LayerNorm + gate(z) ONCE, then out-proj in two
// sequential 48-o passes (ow_s restaged). 16 l per block; grid 196.
__global__ __launch_bounds__(256) void k_lnout(
        const float* __restrict__ y4, const float* __restrict__ z_nat,
        const float* __restrict__ lnw, const float* __restrict__ lnb,
        const float* __restrict__ ow, float* __restrict__ out) {
    __shared__ float yv[16 * 196];                 // 12.5 KB
    __shared__ float ow_s[48 * 196];               // 37.6 KB
    __shared__ float mean_s[16], inv_s[16];
    const int l0 = blockIdx.x * 16;
    const int tid = threadIdx.x;
    // merge 4 directions: float4 over p for each d
    for (int i = tid; i < DI * 4; i += 256) {
        int d = i >> 2, q = i & 3;
        size_t off = (size_t)d * LL + l0 + 4 * q;
        float4 a = *(const float4*)&y4[off];
        float4 b = *(const float4*)&y4[(size_t)DI * LL + off];
        float4 c2 = *(const float4*)&y4[(size_t)(2 * DI) * LL + off];
        float4 e = *(const float4*)&y4[(size_t)(3 * DI) * LL + off];
        int p = 4 * q;
        yv[(p + 0) * 196 + d] = a.x + b.x + c2.x + e.x;
        yv[(p + 1) * 196 + d] = a.y + b.y + c2.y + e.y;
        yv[(p + 2) * 196 + d] = a.z + b.z + c2.z + e.z;
        yv[(p + 3) * 196 + d] = a.w + b.w + c2.w + e.w;
    }
    __syncthreads();
    // LN stats: 16 lanes per p
    {
        int p = tid >> 4, e = tid & 15;
        float s1 = 0.f;
#pragma unroll
        for (int m = 0; m < 12; ++m) s1 += yv[p * 196 + e + 16 * m];
        s1 += __shfl_xor(s1, 8, 64);
        s1 += __shfl_xor(s1, 4, 64);
        s1 += __shfl_xor(s1, 2, 64);
        s1 += __shfl_xor(s1, 1, 64);
        float mean = s1 * (1.f / DI);
        float s2 = 0.f;
#pragma unroll
        for (int m = 0; m < 12; ++m) {
            float dv = yv[p * 196 + e + 16 * m] - mean;
            s2 = fmaf(dv, dv, s2);
        }
        s2 += __shfl_xor(s2, 8, 64);
        s2 += __shfl_xor(s2, 4, 64);
        s2 += __shfl_xor(s2, 2, 64);
        s2 += __shfl_xor(s2, 1, 64);
        if (e == 0) {
            mean_s[p] = mean;
            inv_s[p] = rsqrtf(s2 * (1.f / DI) + 1e-5f);
        }
    }
    __syncthreads();
    // normalize + gate (float4 over d) — done ONCE
    for (int i = tid; i < 16 * 48; i += 256) {
        int p = i / 48, q = i % 48;
        float4 z4 = *(const float4*)&z_nat[(size_t)(l0 + p) * DI + 4 * q];
        float4 w4 = *(const float4*)&lnw[4 * q];
        float4 b4 = *(const float4*)&lnb[4 * q];
        float4 yy = *(const float4*)&yv[p * 196 + 4 * q];
        float m = mean_s[p], iv = inv_s[p];
        yy.x = ((yy.x - m) * iv * w4.x + b4.x) * z4.x;
        yy.y = ((yy.y - m) * iv * w4.y + b4.y) * z4.y;
        yy.z = ((yy.z - m) * iv * w4.z + b4.z) * z4.z;
        yy.w = ((yy.w - m) * iv * w4.w + b4.w) * z4.w;
        *(float4*)&yv[p * 196 + 4 * q] = yy;
    }
    // out-proj: two sequential 48-o passes, restaging ow_s
    const int ty = tid >> 4, tx = tid & 15;        // ty: l, tx: o
#pragma unroll
    for (int pass = 0; pass < 2; ++pass) {
        __syncthreads();
        for (int i = tid; i < 48 * 48; i += 256) {
            int o = i / 48, q = i % 48;
            *(float4*)&ow_s[o * 196 + 4 * q] =
                *(const float4*)&ow[(size_t)(pass * 48 + o) * DI + 4 * q];
        }
        __syncthreads();
        float acc[3] = {};
        for (int dd = 0; dd < DI; dd += 4) {
            float4 a0 = *(const float4*)&yv[ty * 196 + dd];
#pragma unroll
            for (int j = 0; j < 3; ++j) {
                float4 bv = *(const float4*)&ow_s[(tx + 16 * j) * 196 + dd];
                acc[j] += a0.x * bv.x + a0.y * bv.y + a0.z * bv.z + a0.w * bv.w;
            }
        }
#pragma unroll
        for (int j = 0; j < 3; ++j)
            out[(size_t)(l0 + ty) * DM + pass * 48 + tx + 16 * j] = acc[j];
    }
}

extern "C" void kernel_launch(void* const* d_in, const int* in_sizes, int n_in,
                              void* d_out, int out_size, void* d_ws, size_t ws_size,
                              hipStream_t stream) {
    const float* x    = (const float*)d_in[0];
    const float* ipw  = (const float*)d_in[1];
    const float* cw   = (const float*)d_in[2];
    const float* cb   = (const float*)d_in[3];
    const float* xpw  = (const float*)d_in[4];
    const float* dtw  = (const float*)d_in[5];
    const float* dtb  = (const float*)d_in[6];
    const float* alog = (const float*)d_in[7];
    const float* Dsp  = (const float*)d_in[8];
    const float* lnw  = (const float*)d_in[9];
    const float* lnb  = (const float*)d_in[10];
    const float* ow   = (const float*)d_in[11];
    float* out = (float*)d_out;

    float* ws     = (float*)d_ws;
    float* xc_t   = ws;                             // DI*LL (dead after convT)
    float* z_nat  = xc_t + DI * LL;                 // LL*DI
    float* xconv  = z_nat + DI * LL;                // DI*LL
    float* xs1    = xconv + DI * LL;                // DI*LL
    float* Bn     = xs1 + DI * LL;                  // KK*LL*NS
    float* Cn     = Bn + (size_t)KK * LL * NS;      // KK*LL*NS
    float* delta  = Cn + (size_t)KK * LL * NS;      // KK*DI*LL
    float* y4     = delta + (size_t)KK * DI * LL;   // KK*DI*LL (natural p)

    k_inproj <<<dim3(LL / 32, 12), 256, 0, stream>>>(x, ipw, xc_t, z_nat);
    k_convT  <<<dim3(DI, 4), 256, 0, stream>>>(xc_t, cw, cb, xconv, xs1);
    k_xdblD  <<<dim3(LL / 16, KK), 256, 0, stream>>>(xconv, xs1, xpw, dtw, dtb, Bn, Cn, delta);
    k_scan   <<<KK * DI, 512, 0, stream>>>(delta, Bn, Cn, xconv, xs1, alog, Dsp, y4);
    k_lnout  <<<LL / 16, 256, 0, stream>>>(y4, z_nat, lnw, lnb, ow, out);
}